// Round 9
// baseline (665.217 us; speedup 1.0000x reference)
//
#include <hip/hip_runtime.h>
#include <hip/hip_bf16.h>
#include <stdint.h>

typedef __hip_bfloat16 bf16;
typedef short bf16x8 __attribute__((ext_vector_type(8)));
typedef short s4v    __attribute__((ext_vector_type(4)));
typedef float f32x4  __attribute__((ext_vector_type(4)));

constexpr int B_  = 8;
constexpr int PQ_ = 900;
constexpr int C_  = 256;
constexpr int NH_ = 8;
constexpr int L_  = 4;
constexpr int P_  = 4;
constexpr int FF_ = 2048;
constexpr int DH_ = 32;
constexpr int PK_ = 20197;
constexpr int VLD = 960;    // VT row length (15 s-tiles of 64, zero-padded past 900)
constexpr int VTILES = 2525;            // (B*PK + 63)/64 value M-tiles
constexpr int64_t FFS = (int64_t)B_ * PQ_ * C_;   // 1,843,200 elems per FF2 partial

__device__ __forceinline__ short f2b(float f) {
    __hip_bfloat16 h = __float2bfloat16(f);
    union { __hip_bfloat16 h; short s; } u; u.h = h; return u.s;
}
__device__ __forceinline__ float b2f(short s) {
    union { short s; __hip_bfloat16 h; } u; u.s = s; return __bfloat162float(u.h);
}

// ---------------------------------------------------------------------------
// Batched fp32 -> bf16 weight conversion, one launch for all 8 weight mats.
// ---------------------------------------------------------------------------
__launch_bounds__(256)
__global__ void wcvt_kernel(const float* __restrict__ p0, const float* __restrict__ p1,
                            const float* __restrict__ p2, const float* __restrict__ p3,
                            const float* __restrict__ p4, const float* __restrict__ p5,
                            const float* __restrict__ p6, const float* __restrict__ p7,
                            short* __restrict__ dst)
{
    const int g = (blockIdx.x * 256 + threadIdx.x) * 4;
    const float* src; int off;
    if      (g < 196608)  { src = p0; off = 0; }
    else if (g < 262144)  { src = p1; off = 196608; }
    else if (g < 327680)  { src = p2; off = 262144; }
    else if (g < 360448)  { src = p3; off = 327680; }
    else if (g < 425984)  { src = p4; off = 360448; }
    else if (g < 491520)  { src = p5; off = 425984; }
    else if (g < 1015808) { src = p6; off = 491520; }
    else                  { src = p7; off = 1015808; }
    float4 v = *(const float4*)(src + (g - off));
    s4v pk = {f2b(v.x), f2b(v.y), f2b(v.z), f2b(v.w)};
    *(s4v*)&dst[g] = pk;
}

// ---------------------------------------------------------------------------
// UNION kernel: blocks [0, VTILES) = fused key-transpose + value projection
// (vgemm3 algorithm at 256 threads / 4 waves); blocks [VTILES, VTILES+960) =
// fused flash attention (bounded-score softmax, r8 math). The two tasks are
// data-independent; grid-union gives true concurrency on one stream so the
// latency bubbles of one fill with the other's work.
// Shared 32 KB buffer: vgemm As (64x256 swizzled, overlaid C-stage) / attn Pl.
// ---------------------------------------------------------------------------
__launch_bounds__(256)
__global__ void union_kernel(const float* __restrict__ key, const short* __restrict__ Wv,
                             const float* __restrict__ bias, short* __restrict__ value,
                             int Mb,
                             const short* __restrict__ qkv, const short* __restrict__ VT,
                             short* __restrict__ attno)
{
    __shared__ short Sh[64 * 256];    // 32 KB
    const int tid = threadIdx.x;
    const int wv = tid >> 6, lane = tid & 63;
    const int quad = lane >> 4, lrow = lane & 15;

    if (blockIdx.x < VTILES) {
        // ================= value-projection path =================
        constexpr int CST = 40;
        short* As = Sh;

        const int m0 = blockIdx.x * 64;
        const int gm = m0 + lane;
        const bool va = gm < Mb;
        int b = 0, s = 0;
        if (va) { b = gm / PK_; s = gm - b * PK_; }
        const int64_t rbase = (int64_t)(b * 256) * PK_ + s;

        // stage: wave wv covers c = wv*64 .. wv*64+63, lane = s-row
#pragma unroll
        for (int jj = 0; jj < 8; ++jj) {
            short pk[8];
#pragma unroll
            for (int j = 0; j < 8; ++j) {
                const int c = wv * 64 + jj * 8 + j;
                pk[j] = f2b(va ? key[rbase + (int64_t)c * PK_] : 0.f);
            }
            const int slot = wv * 8 + jj;
            const int phys = (slot + lane) & 31;
            *(bf16x8*)&As[lane * 256 + phys * 8] = *(const bf16x8*)pk;
        }
        __syncthreads();

        float bia[4];
#pragma unroll
        for (int nf = 0; nf < 4; ++nf) bia[nf] = bias[wv * 64 + nf * 16 + lrow];

        f32x4 acc[4][4];
#pragma unroll
        for (int mf = 0; mf < 4; ++mf)
#pragma unroll
            for (int nf = 0; nf < 4; ++nf) acc[mf][nf] = (f32x4){0.f, 0.f, 0.f, 0.f};

#pragma unroll
        for (int kh = 0; kh < 8; ++kh) {
            bf16x8 a[4];
#pragma unroll
            for (int mf = 0; mf < 4; ++mf) {
                const int r = mf * 16 + lrow;
                const int phys = ((kh * 4 + quad) + r) & 31;
                a[mf] = *(const bf16x8*)&As[r * 256 + phys * 8];
            }
            bf16x8 wf[4];
#pragma unroll
            for (int nf = 0; nf < 4; ++nf)
                wf[nf] = *(const bf16x8*)&Wv[(int64_t)(wv * 64 + nf * 16 + lrow) * 256 + kh * 32 + quad * 8];
#pragma unroll
            for (int mf = 0; mf < 4; ++mf)
#pragma unroll
                for (int nf = 0; nf < 4; ++nf)
                    acc[mf][nf] = __builtin_amdgcn_mfma_f32_16x16x32_bf16(a[mf], wf[nf], acc[mf][nf], 0, 0, 0);
        }
        __syncthreads();   // all As reads done before C-stage overwrites

        // C-stage (wave-private 64x40 region) + full-line b128 stores
        short* Cs = &Sh[wv * 64 * CST];
#pragma unroll
        for (int nf = 0; nf < 4; ++nf)
#pragma unroll
            for (int mf = 0; mf < 4; ++mf)
#pragma unroll
                for (int r = 0; r < 4; ++r)
                    Cs[(mf * 16 + quad * 4 + r) * CST + nf * 16 + lrow] = f2b(acc[mf][nf][r] + bia[nf]);
        // wave-internal ordering: own-wave reads need no barrier
#pragma unroll
        for (int jj = 0; jj < 8; ++jj) {
            const int row = (lane >> 3) + jj * 8;
            const int rr = m0 + row;
            bf16x8 pk = *(const bf16x8*)&Cs[row * CST + (lane & 7) * 8];
            if (rr < Mb)
                *(bf16x8*)&value[(int64_t)rr * 256 + wv * 64 + (lane & 7) * 8] = pk;
        }
        return;
    }

    // ================= attention path =================
    const int bid2 = blockIdx.x - VTILES;
    const int qt = bid2 % 15, bh = bid2 / 15;
    const int b = bh >> 3, h = bh & 7;
    const int q0 = qt * 64 + wv * 16;
    const float iscale = 0.17677669529663687f; // 1/sqrt(32)

    short* Pw = &Sh[wv * 16 * 72];

    bf16x8 aq = {0, 0, 0, 0, 0, 0, 0, 0};
    {
        const int q = q0 + lrow;
        if (q < 900)
            aq = *(const bf16x8*)&qkv[((int64_t)(b * 900 + q)) * 768 + h * 32 + quad * 8];
    }

    float lsum[4];
    f32x4 o[2] = {{0.f, 0.f, 0.f, 0.f}, {0.f, 0.f, 0.f, 0.f}};
#pragma unroll
    for (int r = 0; r < 4; ++r) lsum[r] = 0.f;

    for (int st = 0; st < 15; ++st) {
        const int s0 = st * 64;
        f32x4 sc[4];
#pragma unroll
        for (int nf = 0; nf < 4; ++nf) {
            const int s = s0 + nf * 16 + lrow;
            bf16x8 kb = {0, 0, 0, 0, 0, 0, 0, 0};
            if (s < 900)
                kb = *(const bf16x8*)&qkv[((int64_t)(b * 900 + s)) * 768 + 256 + h * 32 + quad * 8];
            sc[nf] = __builtin_amdgcn_mfma_f32_16x16x32_bf16(aq, kb, (f32x4){0.f, 0.f, 0.f, 0.f}, 0, 0, 0);
        }
#pragma unroll
        for (int nf = 0; nf < 4; ++nf) {
            const int s = s0 + nf * 16 + lrow;
            if (s >= 900) sc[nf] = (f32x4){-1e30f, -1e30f, -1e30f, -1e30f};
            else {
#pragma unroll
                for (int r = 0; r < 4; ++r) sc[nf][r] *= iscale;
            }
        }
        float ps[4][4];
#pragma unroll
        for (int r = 0; r < 4; ++r) {
            float s4 = 0.f;
#pragma unroll
            for (int nf = 0; nf < 4; ++nf) {
                const float p = __expf(sc[nf][r]);
                ps[nf][r] = p;
                s4 += p;
            }
#pragma unroll
            for (int off = 1; off < 16; off <<= 1)
                s4 += __shfl_xor(s4, off, 64);
            lsum[r] += s4;
        }
        // P -> per-wave LDS (C-layout scatter), read back as A-frags
#pragma unroll
        for (int nf = 0; nf < 4; ++nf)
#pragma unroll
            for (int r = 0; r < 4; ++r)
                Pw[(quad * 4 + r) * 72 + nf * 16 + lrow] = f2b(ps[nf][r]);
#pragma unroll
        for (int kh = 0; kh < 2; ++kh) {
            bf16x8 pa = *(const bf16x8*)&Pw[lrow * 72 + kh * 32 + quad * 8];
#pragma unroll
            for (int nf2 = 0; nf2 < 2; ++nf2) {
                const int d = nf2 * 16 + lrow;
                bf16x8 vb = *(const bf16x8*)&VT[((int64_t)bh * 32 + d) * VLD + s0 + kh * 32 + quad * 8];
                o[nf2] = __builtin_amdgcn_mfma_f32_16x16x32_bf16(pa, vb, o[nf2], 0, 0, 0);
            }
        }
    }
#pragma unroll
    for (int r = 0; r < 4; ++r) {
        const int q = q0 + quad * 4 + r;
        if (q < 900) {
            const float inv = 1.f / lsum[r];
#pragma unroll
            for (int nf2 = 0; nf2 < 2; ++nf2)
                attno[((int64_t)(b * 900 + q)) * 256 + h * 32 + nf2 * 16 + lrow] = f2b(o[nf2][r] * inv);
        }
    }
}

// ---------------------------------------------------------------------------
// Generalized batched MFMA GEMM. MF = 16-row M-fragments per tile.
// Two-segment bias: col < nsplit -> bias[col], else bias2[col-nsplit].
// ---------------------------------------------------------------------------
template <int NF, int MF, bool DBUF, bool AF32, bool WF32, bool CF32, bool RELU>
__launch_bounds__(256)
__global__ void mfma_gemm(const void* __restrict__ Ap, const void* __restrict__ Wp,
                          const float* __restrict__ bias, void* __restrict__ Cp,
                          int Mb, int N, int K, int tilesM,
                          int ldA, int ldW, int ldC, int nbI,
                          int64_t sAo, int64_t sAi, int64_t sWo, int64_t sWi,
                          int64_t sCo, int64_t sCi, float scale,
                          const float* __restrict__ bias2, int nsplit)
{
    constexpr int BM  = MF * 16;
    constexpr int BN  = 64 * NF;
    constexpr int LDR = 72;
    constexpr int NB  = DBUF ? 2 : 1;
    constexpr int TPR = 256 / BM;
    constexpr int SPT = 64 / TPR;
    constexpr int CHA = SPT / 8;
    __shared__ short As[NB * BM * LDR];
    __shared__ short Ws[NB * BN * LDR];

    const int tid   = threadIdx.x;
    const int batch = blockIdx.y / tilesM;
    const int m0    = (blockIdx.y % tilesM) * BM;
    const int n0    = blockIdx.x * BN;
    const int outer = batch / nbI, inner = batch % nbI;
    const int64_t offA = (int64_t)outer * sAo + (int64_t)inner * sAi;
    const int64_t offW = (int64_t)outer * sWo + (int64_t)inner * sWi;
    const int64_t offC = (int64_t)outer * sCo + (int64_t)inner * sCi;

    const int w = tid >> 6, lane = tid & 63;
    const int quad = lane >> 4, lrow = lane & 15;
    const int colbase = n0 + w * 16 * NF;

    const int smA = tid / TPR;
    const int skA = (tid % TPR) * SPT;
    const int smW = tid >> 2;
    const int skW = (tid & 3) * 16;

    const int T = (K + 63) / 64;

    bf16x8 areg[CHA];
    bf16x8 wreg[2 * NF];

    auto stageA = [&](int t) {
        const int k0 = t * 64;
        const int gm = m0 + smA;
#pragma unroll
        for (int c = 0; c < CHA; ++c) {
            const int k = k0 + skA + c * 8;
            bf16x8 pk = {0, 0, 0, 0, 0, 0, 0, 0};
            if (gm < Mb && k + 8 <= K) {
                if (AF32) {
                    const float* s = (const float*)Ap + offA + (int64_t)gm * ldA + k;
                    float4 u0 = *(const float4*)s;
                    float4 u1 = *(const float4*)(s + 4);
                    pk = (bf16x8){f2b(u0.x), f2b(u0.y), f2b(u0.z), f2b(u0.w),
                                  f2b(u1.x), f2b(u1.y), f2b(u1.z), f2b(u1.w)};
                } else {
                    pk = *(const bf16x8*)((const short*)Ap + offA + (int64_t)gm * ldA + k);
                }
            }
            areg[c] = pk;
        }
    };
    auto stageW = [&](int t) {
        const int k0 = t * 64;
#pragma unroll
        for (int j = 0; j < NF; ++j) {
            const int gn = n0 + j * 64 + smW;
#pragma unroll
            for (int c = 0; c < 2; ++c) {
                const int k = k0 + skW + c * 8;
                bf16x8 pk = {0, 0, 0, 0, 0, 0, 0, 0};
                if (gn < N && k + 8 <= K) {
                    if (WF32) {
                        const float* s = (const float*)Wp + offW + (int64_t)gn * ldW + k;
                        float4 u0 = *(const float4*)s;
                        float4 u1 = *(const float4*)(s + 4);
                        pk = (bf16x8){f2b(u0.x), f2b(u0.y), f2b(u0.z), f2b(u0.w),
                                      f2b(u1.x), f2b(u1.y), f2b(u1.z), f2b(u1.w)};
                    } else {
                        pk = *(const bf16x8*)((const short*)Wp + offW + (int64_t)gn * ldW + k);
                    }
                }
                wreg[j * 2 + c] = pk;
            }
        }
    };
    auto writeLDS = [&](int buf) {
#pragma unroll
        for (int c = 0; c < CHA; ++c)
            *(bf16x8*)&As[(buf * BM + smA) * LDR + skA + c * 8] = areg[c];
#pragma unroll
        for (int j = 0; j < NF; ++j)
#pragma unroll
            for (int c = 0; c < 2; ++c)
                *(bf16x8*)&Ws[(buf * BN + j * 64 + smW) * LDR + skW + c * 8] = wreg[j * 2 + c];
    };

    f32x4 acc[MF][NF];
#pragma unroll
    for (int i = 0; i < MF; ++i)
#pragma unroll
        for (int j = 0; j < NF; ++j) acc[i][j] = (f32x4){0.f, 0.f, 0.f, 0.f};

    auto compute = [&](int buf) {
        bf16x8 a[MF][2], bb[NF][2];
#pragma unroll
        for (int kh = 0; kh < 2; ++kh) {
#pragma unroll
            for (int mf = 0; mf < MF; ++mf)
                a[mf][kh] = *(const bf16x8*)&As[(buf * BM + mf * 16 + lrow) * LDR + kh * 32 + quad * 8];
#pragma unroll
            for (int nf = 0; nf < NF; ++nf)
                bb[nf][kh] = *(const bf16x8*)&Ws[(buf * BN + w * 16 * NF + nf * 16 + lrow) * LDR + kh * 32 + quad * 8];
        }
#pragma unroll
        for (int kh = 0; kh < 2; ++kh)
#pragma unroll
            for (int mf = 0; mf < MF; ++mf)
#pragma unroll
                for (int nf = 0; nf < NF; ++nf)
                    acc[mf][nf] = __builtin_amdgcn_mfma_f32_16x16x32_bf16(a[mf][kh], bb[nf][kh], acc[mf][nf], 0, 0, 0);
    };

    if (DBUF) {
        stageA(0); stageW(0); writeLDS(0);
        __syncthreads();
        for (int t = 0; t < T; ++t) {
            const int cur = t & 1;
            if (t + 1 < T) { stageA(t + 1); stageW(t + 1); }
            compute(cur);
            if (t + 1 < T) {
                writeLDS(cur ^ 1);
                __syncthreads();
            }
        }
    } else {
        for (int t = 0; t < T; ++t) {
            stageA(t); stageW(t);
            if (t > 0) __syncthreads();
            writeLDS(0);
            __syncthreads();
            compute(0);
        }
    }

#pragma unroll
    for (int nf = 0; nf < NF; ++nf) {
        const int col = colbase + nf * 16 + lrow;
        if (col >= N) continue;
        float bia;
        if (col < nsplit) bia = bias ? bias[col] : 0.f;
        else              bia = bias2[col - nsplit];
#pragma unroll
        for (int mf = 0; mf < MF; ++mf) {
            const int row0 = m0 + mf * 16 + quad * 4;
#pragma unroll
            for (int r = 0; r < 4; ++r) {
                const int rr = row0 + r;
                if (rr < Mb) {
                    float v = acc[mf][nf][r] * scale + bia;
                    if (RELU) v = fmaxf(v, 0.f);
                    const int64_t idx = offC + (int64_t)rr * ldC + col;
                    if (CF32) ((float*)Cp)[idx] = v;
                    else      ((short*)Cp)[idx] = f2b(v);
                }
            }
        }
    }
}

template <int NF, int MF, bool DBUF, bool AF32, bool WF32, bool CF32, bool RELU>
static void mfma_launch(const void* A, const void* W, const float* bias, void* Cp,
                        int nb, int nbI, int Mb, int N, int K,
                        int ldA, int ldW, int ldC,
                        int64_t sAo, int64_t sAi, int64_t sWo, int64_t sWi,
                        int64_t sCo, int64_t sCi, float scale, hipStream_t stream,
                        const float* bias2 = nullptr, int nsplit = 1 << 30)
{
    constexpr int BM = MF * 16;
    int tilesM = (Mb + BM - 1) / BM;
    dim3 grid((N + 64 * NF - 1) / (64 * NF), nb * tilesM);
    mfma_gemm<NF, MF, DBUF, AF32, WF32, CF32, RELU><<<grid, 256, 0, stream>>>(
        A, W, bias, Cp, Mb, N, K, tilesM, ldA, ldW, ldC, nbI,
        sAo, sAi, sWo, sWi, sCo, sCi, scale, bias2, nsplit);
}

// ---------------------------------------------------------------------------
// 32x32 tile transpose: dst[b][s][c] (bf16, row=256) = src[b*sbs + (c0+c)*ldS + s]
// ---------------------------------------------------------------------------
__launch_bounds__(256)
__global__ void transpose_kernel(const float* __restrict__ src, short* __restrict__ dst,
                                 int Scount, int ldS, int64_t sbs, int64_t dbs)
{
    const int tid = threadIdx.x;
    const int b = blockIdx.z;
    const int s0 = blockIdx.x * 32, c0 = blockIdx.y * 32;
    __shared__ float t[32][33];
    {
        const int c_l = tid >> 3, sq = (tid & 7) * 4;
        const int64_t base = (int64_t)b * sbs + (int64_t)(c0 + c_l) * ldS;
#pragma unroll
        for (int i = 0; i < 4; ++i) {
            const int s = s0 + sq + i;
            t[c_l][sq + i] = (s < Scount) ? src[base + s] : 0.f;
        }
    }
    __syncthreads();
    {
        const int s_l = tid >> 3, cq = (tid & 7) * 4;
        const int s = s0 + s_l;
        if (s < Scount) {
            s4v pk = {f2b(t[cq + 0][s_l]), f2b(t[cq + 1][s_l]),
                      f2b(t[cq + 2][s_l]), f2b(t[cq + 3][s_l])};
            *(s4v*)&dst[(int64_t)b * dbs + (int64_t)s * 256 + c0 + cq] = pk;
        }
    }
}

// ---------------------------------------------------------------------------
// VT[bh][d][s] (bf16, ld=960, s>=900 zero) from bf16 qkv (B*900, 768)
// ---------------------------------------------------------------------------
__launch_bounds__(256)
__global__ void vt_kernel(const short* __restrict__ qkv, short* __restrict__ VT)
{
    const int tid = threadIdx.x;
    const int bh = blockIdx.y, b = bh >> 3, h = bh & 7;
    const int s0 = blockIdx.x * 32;
    __shared__ short t[32][36];
    {
        const int s_l = tid >> 3, dq = (tid & 7) * 4;
        const int s = s0 + s_l;
        s4v pk = {0, 0, 0, 0};
        if (s < 900)
            pk = *(const s4v*)&qkv[((int64_t)(b * 900 + s)) * 768 + 512 + h * 32 + dq];
        *(s4v*)&t[s_l][dq] = pk;
    }
    __syncthreads();
    {
        const int d = tid >> 3, sq = (tid & 7) * 4;
        s4v pk = {t[sq + 0][d], t[sq + 1][d], t[sq + 2][d], t[sq + 3][d]};
        *(s4v*)&VT[((int64_t)bh * 32 + d) * VLD + s0 + sq] = pk;
    }
}

// ---------------------------------------------------------------------------
// Residual + LayerNorm over C=256, one block per (b,t). Wave-shfl reduction.
// MODE 0: res = query (B,C,PQ) fp32 transposed-read; out q1 fp32 + q1b bf16
// MODE 1: res = q1 fp32 (BT,C);                      out q2nb bf16 only
// MODE 2: res = q2nb bf16; y = 4 FF2 split-K partials (stride FFS) + eb bias;
//         out d_out fp32 (B,C,PQ)
// ---------------------------------------------------------------------------
template <int MODE>
__launch_bounds__(256)
__global__ void ln_kernel(const float* __restrict__ y, const void* __restrict__ res,
                          const float* __restrict__ g, const float* __restrict__ be,
                          float* __restrict__ out_f, short* __restrict__ out_b,
                          const float* __restrict__ eb)
{
    const int bt = blockIdx.x;
    const int b = bt / PQ_, t = bt % PQ_;
    const int c = threadIdx.x;
    const int wv = c >> 6, lane = c & 63;

    float r;
    if (MODE == 0)      r = ((const float*)res)[((int64_t)b * C_ + c) * PQ_ + t];
    else if (MODE == 1) r = ((const float*)res)[(int64_t)bt * C_ + c];
    else                r = b2f(((const short*)res)[(int64_t)bt * C_ + c]);

    float yv;
    if (MODE == 2) {
        yv = eb[c];
#pragma unroll
        for (int i = 0; i < 4; ++i)
            yv += y[(int64_t)i * FFS + (int64_t)bt * C_ + c];
    } else {
        yv = y[(int64_t)bt * C_ + c];
    }
    const float v = r + yv;

    __shared__ float p1[4], p2[4];
    float a = v, sq = v * v;
#pragma unroll
    for (int off = 32; off > 0; off >>= 1) {
        a  += __shfl_xor(a, off, 64);
        sq += __shfl_xor(sq, off, 64);
    }
    if (lane == 0) { p1[wv] = a; p2[wv] = sq; }
    __syncthreads();
    const float s1 = p1[0] + p1[1] + p1[2] + p1[3];
    const float s2 = p2[0] + p2[1] + p2[2] + p2[3];
    const float mean = s1 * (1.f / C_);
    const float var  = s2 * (1.f / C_) - mean * mean;
    const float o = (v - mean) * rsqrtf(var + 1e-5f) * g[c] + be[c];

    if (MODE == 0) { out_f[(int64_t)bt * C_ + c] = o; out_b[(int64_t)bt * C_ + c] = f2b(o); }
    else if (MODE == 1) out_b[(int64_t)bt * C_ + c] = f2b(o);
    else out_f[((int64_t)b * C_ + c) * PQ_ + t] = o;
}

// ---------------------------------------------------------------------------
// Fused MS-deformable sampling, v2: 2 queries per block, u32 (bf16x2) gathers.
// Reads offsets+aw-logits from the merged (BT,384) fp32 buffer.
// ---------------------------------------------------------------------------
__launch_bounds__(256)
__global__ void deform_kernel(const float* __restrict__ oa,
                              const float* __restrict__ refp, const short* __restrict__ value,
                              short* __restrict__ samp)
{
    const int half = threadIdx.x >> 7;
    const int t = threadIdx.x & 127;
    const int bt = blockIdx.x * 2 + half;
    const int b = bt / PQ_;
    const int h = t >> 4, dp = t & 15;

    __shared__ float Loff[2][256];
    __shared__ float Law[2][128];
    __shared__ float Lref[2][8];

    Loff[half][t]       = oa[(int64_t)bt * 384 + t];
    Loff[half][t + 128] = oa[(int64_t)bt * 384 + t + 128];
    Law[half][t]        = oa[(int64_t)bt * 384 + 256 + t];
    if (t < 8) Lref[half][t] = refp[(int64_t)bt * 8 + t];
    __syncthreads();

    float m = -1e30f;
#pragma unroll
    for (int i = 0; i < 16; ++i) m = fmaxf(m, Law[half][h * 16 + i]);
    float s = 0.f;
#pragma unroll
    for (int i = 0; i < 16; ++i) s += __expf(Law[half][h * 16 + i] - m);
    const float invs = 1.f / s;

    const int HLc[4] = {100, 50, 25, 13};
    const int WLc[4] = {152, 76, 38, 19};
    const int STc[4] = {0, 15200, 19000, 19950};

    float acc0 = 0.f, acc1 = 0.f;
#pragma unroll
    for (int l = 0; l < L_; ++l) {
        const int Hl = HLc[l], Wl = WLc[l], st0 = STc[l];
        const float fx = Lref[half][l * 2 + 0], fy = Lref[half][l * 2 + 1];
#pragma unroll
        for (int p = 0; p < P_; ++p) {
            const float ox = Loff[half][h * 32 + l * 8 + p * 2 + 0];
            const float oy = Loff[half][h * 32 + l * 8 + p * 2 + 1];
            const float x = (fx + ox / (float)Wl) * (float)Wl - 0.5f;
            const float y = (fy + oy / (float)Hl) * (float)Hl - 0.5f;
            const float x0f = floorf(x), y0f = floorf(y);
            const int x0 = (int)x0f, y0 = (int)y0f;
            const float lw = x - x0f, lh = y - y0f;
            const float w00 = (1.f - lw) * (1.f - lh), w10 = lw * (1.f - lh);
            const float w01 = (1.f - lw) * lh,         w11 = lw * lh;
            const float aww = __expf(Law[half][h * 16 + l * 4 + p] - m) * invs;

            float sv0 = 0.f, sv1 = 0.f;
            int ix, iy; float w;
#pragma unroll
            for (int cidx = 0; cidx < 4; ++cidx) {
                if (cidx == 0) { ix = x0;     iy = y0;     w = w00; }
                if (cidx == 1) { ix = x0 + 1; iy = y0;     w = w10; }
                if (cidx == 2) { ix = x0;     iy = y0 + 1; w = w01; }
                if (cidx == 3) { ix = x0 + 1; iy = y0 + 1; w = w11; }
                if (ix >= 0 && ix < Wl && iy >= 0 && iy < Hl) {
                    const int64_t vi = ((int64_t)(b * PK_ + st0 + iy * Wl + ix)) * 256 + h * 32 + dp * 2;
                    const uint32_t pr = *(const uint32_t*)&value[vi];
                    sv0 += w * b2f((short)(pr & 0xffff));
                    sv1 += w * b2f((short)(pr >> 16));
                }
            }
            acc0 += sv0 * aww;
            acc1 += sv1 * aww;
        }
    }
    union { uint32_t u; short s2[2]; } o;
    o.s2[0] = f2b(acc0);
    o.s2[1] = f2b(acc1);
    *(uint32_t*)&samp[(int64_t)bt * 256 + h * 32 + dp * 2] = o.u;
}

// ---------------------------------------------------------------------------
extern "C" void kernel_launch(void* const* d_in, const int* in_sizes, int n_in,
                              void* d_out, int out_size, void* d_ws, size_t ws_size,
                              hipStream_t stream)
{
    const float* query = (const float*)d_in[0];
    const float* key   = (const float*)d_in[1];
    const float* refp  = (const float*)d_in[4];
    const float* W_in  = (const float*)d_in[5];
    const float* b_in  = (const float*)d_in[6];
    const float* W_out = (const float*)d_in[7];
    const float* b_out = (const float*)d_in[8];
    const float* W_off = (const float*)d_in[9];
    const float* b_off = (const float*)d_in[10];
    const float* W_aw  = (const float*)d_in[11];
    const float* b_aw  = (const float*)d_in[12];
    const float* W_v   = (const float*)d_in[13];
    const float* b_v   = (const float*)d_in[14];
    const float* W_o   = (const float*)d_in[15];
    const float* b_o   = (const float*)d_in[16];
    const float* W1    = (const float*)d_in[17];
    const float* b1    = (const float*)d_in[18];
    const float* W2    = (const float*)d_in[19];
    const float* b2    = (const float*)d_in[20];
    const float* g1    = (const float*)d_in[21];
    const float* be1   = (const float*)d_in[22];
    const float* g2    = (const float*)d_in[23];
    const float* be2   = (const float*)d_in[24];
    const float* g3    = (const float*)d_in[25];
    const float* be3   = (const float*)d_in[26];

    // Workspace plan:
    //  X [62,259,200]: {qkv bf16 | queryT | VT | attno} -> later ffh
    //  Y: proj ; Z1: q1 ; Wa: q1b -> samp ; Wb: (spare) -> q2nb
    //  VA: value (B*PK,256) bf16 ; WB: bf16 weights
    //  OA: merged offb+awl (BT,384) fp32 ; FFP: 4 FF2 split-K partials
    char* X  = (char*)d_ws;
    char* Yb = X + 62259200;
    char* Z1 = Yb + 7372800;
    char* Wa = Z1 + 7372800;
    char* Wb_ = Wa + 3686400;
    char* VA = Wb_ + 3686400;
    char* WB = VA + 82726912;
    char* OA = WB + 3080192;
    char* FFP = OA + 11059200;

    short* qkvb   = (short*)X;                 // (B*900, 768) bf16
    short* queryT = (short*)(X + 11059200);
    short* VT     = (short*)(X + 14745600);    // 64*32*960*2 = 3,932,160
    short* attno  = (short*)(X + 18677760);
    short* ffh    = (short*)X;
    float* proj   = (float*)Yb;
    float* q1     = (float*)Z1;
    short* q1b    = (short*)Wa;
    short* samp   = (short*)Wa;
    short* q2nb   = (short*)Wb_;
    short* value  = (short*)VA;
    float* oa     = (float*)OA;
    float* ffp    = (float*)FFP;

    short* WBs    = (short*)WB;
    short* Wb_in  = WBs;             // 196608
    short* Wb_out = WBs + 196608;    // 65536
    short* Wb_off = WBs + 262144;    // 65536 (W_aw contiguous after: merged N=384)
    short* Wb_v   = WBs + 360448;    // 65536
    short* Wb_o   = WBs + 425984;    // 65536
    short* Wb1    = WBs + 491520;    // 524288
    short* Wb2    = WBs + 1015808;   // 524288

    // 0. convert all weights fp32 -> bf16 (one launch)
    wcvt_kernel<<<1504, 256, 0, stream>>>(W_in, W_out, W_off, W_aw, W_v, W_o, W1, W2, WBs);
    // 1. queryT = bf16 transpose of query
    transpose_kernel<<<dim3(29, 8, B_), 256, 0, stream>>>(query, queryT, PQ_, PQ_,
                                                          (int64_t)C_ * PQ_, (int64_t)PQ_ * C_);
    // 2. qkv = queryT @ W_in^T + b_in  (bf16 out)
    mfma_launch<1, 4, true, false, false, false, false>(queryT, Wb_in, b_in, qkvb, 1, 1, B_ * PQ_, 768, 256,
                                                        256, 256, 768, 0, 0, 0, 0, 0, 0, 1.f, stream);
    // 3. VT (zero-padded to 960)
    vt_kernel<<<dim3(30, 64), 256, 0, stream>>>(qkvb, VT);
    // 4. UNION: fused flash attention (960 blocks) CONCURRENT WITH
    //    fused key-transpose + value projection (2525 blocks)
    union_kernel<<<VTILES + 960, 256, 0, stream>>>(key, Wb_v, b_v, value, B_ * PK_,
                                                   qkvb, VT, attno);
    // 5. proj = attno @ W_out^T + b_out  (BM=32)
    mfma_launch<1, 2, true, false, false, true, false>(attno, Wb_out, b_out, proj, 1, 1, B_ * PQ_, 256, 256,
                                                       256, 256, 256, 0, 0, 0, 0, 0, 0, 1.f, stream);
    // 6. q1 = LN(x + proj)  (fp32 + bf16)
    ln_kernel<0><<<B_ * PQ_, 256, 0, stream>>>(proj, query, g1, be1, q1, q1b, nullptr);
    // 7. MERGED offsets + aw-logits GEMM: N=384, BM=32
    mfma_launch<1, 2, true, false, false, true, false>(q1b, Wb_off, b_off, oa, 1, 1, B_ * PQ_, 384, 256,
                                                       256, 256, 384, 0, 0, 0, 0, 0, 0, 1.f, stream,
                                                       b_aw, 256);
    // 8. deform (value ready from union, oa ready)
    deform_kernel<<<B_ * PQ_ / 2, 256, 0, stream>>>(oa, refp, value, samp);
    // 9. proj2 = samp @ W_o^T + b_o  (reuse proj buffer; BM=32)
    mfma_launch<1, 2, true, false, false, true, false>(samp, Wb_o, b_o, proj, 1, 1, B_ * PQ_, 256, 256,
                                                       256, 256, 256, 0, 0, 0, 0, 0, 0, 1.f, stream);
    // 10. q2nb = LN(q1 + proj2)  (bf16)
    ln_kernel<1><<<B_ * PQ_, 256, 0, stream>>>(proj, q1, g2, be2, nullptr, q2nb, nullptr);
    // 11. ffh = relu(q2nb @ W1^T + b1)  (bf16)
    mfma_launch<1, 4, true, false, false, false, true>(q2nb, Wb1, b1, ffh, 1, 1, B_ * PQ_, FF_, 256,
                                                       256, 256, FF_, 0, 0, 0, 0, 0, 0, 1.f, stream);
    // 12. FF2 split-K=4: 4 partials (no bias), K-chunks of 512 via batch strides
    mfma_launch<1, 4, true, false, false, true, false>(ffh, Wb2, nullptr, ffp, 4, 1, B_ * PQ_, 256, 512,
                                                       FF_, FF_, 256,
                                                       512, 0, 512, 0, FFS, 0, 1.f, stream);
    // 13. d_out = LN(q2nb + sum(ffp) + b2), transposed to (B,C,PQ)
    ln_kernel<2><<<B_ * PQ_, 256, 0, stream>>>(ffp, q2nb, g3, be3, (float*)d_out, nullptr, b2);

    (void)in_sizes; (void)n_in; (void)out_size; (void)ws_size;
}

// Round 10
// 627.353 us; speedup vs baseline: 1.0604x; 1.0604x over previous
//
#include <hip/hip_runtime.h>
#include <hip/hip_bf16.h>
#include <stdint.h>

typedef __hip_bfloat16 bf16;
typedef short bf16x8 __attribute__((ext_vector_type(8)));
typedef short s4v    __attribute__((ext_vector_type(4)));
typedef float f32x4  __attribute__((ext_vector_type(4)));

constexpr int B_  = 8;
constexpr int PQ_ = 900;
constexpr int C_  = 256;
constexpr int NH_ = 8;
constexpr int L_  = 4;
constexpr int P_  = 4;
constexpr int FF_ = 2048;
constexpr int DH_ = 32;
constexpr int PK_ = 20197;
constexpr int VLD = 960;    // VT row length (15 s-tiles of 64, zero-padded past 900)
constexpr int64_t FFS = (int64_t)B_ * PQ_ * C_;   // 1,843,200 elems per FF2 partial

__device__ __forceinline__ short f2b(float f) {
    __hip_bfloat16 h = __float2bfloat16(f);
    union { __hip_bfloat16 h; short s; } u; u.h = h; return u.s;
}
__device__ __forceinline__ float b2f(short s) {
    union { short s; __hip_bfloat16 h; } u; u.s = s; return __bfloat162float(u.h);
}

// ---------------------------------------------------------------------------
// Batched fp32 -> bf16 weight conversion, one launch for all 8 weight mats.
// ---------------------------------------------------------------------------
__launch_bounds__(256)
__global__ void wcvt_kernel(const float* __restrict__ p0, const float* __restrict__ p1,
                            const float* __restrict__ p2, const float* __restrict__ p3,
                            const float* __restrict__ p4, const float* __restrict__ p5,
                            const float* __restrict__ p6, const float* __restrict__ p7,
                            short* __restrict__ dst)
{
    const int g = (blockIdx.x * 256 + threadIdx.x) * 4;
    const float* src; int off;
    if      (g < 196608)  { src = p0; off = 0; }
    else if (g < 262144)  { src = p1; off = 196608; }
    else if (g < 327680)  { src = p2; off = 262144; }
    else if (g < 360448)  { src = p3; off = 327680; }
    else if (g < 425984)  { src = p4; off = 360448; }
    else if (g < 491520)  { src = p5; off = 425984; }
    else if (g < 1015808) { src = p6; off = 491520; }
    else                  { src = p7; off = 1015808; }
    float4 v = *(const float4*)(src + (g - off));
    s4v pk = {f2b(v.x), f2b(v.y), f2b(v.z), f2b(v.w)};
    *(s4v*)&dst[g] = pk;
}

// ---------------------------------------------------------------------------
// FUSED key-transpose + value projection, v3 (round-6, at latency floor).
// ---------------------------------------------------------------------------
__launch_bounds__(512)
__global__ void vgemm3_kernel(const float* __restrict__ key, const short* __restrict__ Wv,
                              const float* __restrict__ bias, short* __restrict__ value,
                              int Mb)
{
    constexpr int CST = 40;
    __shared__ short Sh[8 * 64 * CST];
    short* As = Sh;

    const int tid = threadIdx.x;
    const int wv = tid >> 6, lane = tid & 63;
    const int quad = lane >> 4, lrow = lane & 15;

    const int m0 = blockIdx.x * 64;
    const int gm = m0 + lane;
    const bool va = gm < Mb;
    int b = 0, s = 0;
    if (va) { b = gm / PK_; s = gm - b * PK_; }
    const int64_t rbase = (int64_t)(b * 256) * PK_ + s;

#pragma unroll
    for (int jj = 0; jj < 4; ++jj) {
        short pk[8];
#pragma unroll
        for (int j = 0; j < 8; ++j) {
            const int c = wv * 32 + jj * 8 + j;
            pk[j] = f2b(va ? key[rbase + (int64_t)c * PK_] : 0.f);
        }
        const int slot = wv * 4 + jj;
        const int phys = (slot + lane) & 31;
        *(bf16x8*)&As[lane * 256 + phys * 8] = *(const bf16x8*)pk;
    }
    __syncthreads();

    float bia[2];
#pragma unroll
    for (int nf = 0; nf < 2; ++nf) bia[nf] = bias[wv * 32 + nf * 16 + lrow];

    f32x4 acc[4][2];
#pragma unroll
    for (int mf = 0; mf < 4; ++mf)
#pragma unroll
        for (int nf = 0; nf < 2; ++nf) acc[mf][nf] = (f32x4){0.f, 0.f, 0.f, 0.f};

#pragma unroll
    for (int kh = 0; kh < 8; ++kh) {
        bf16x8 a[4];
#pragma unroll
        for (int mf = 0; mf < 4; ++mf) {
            const int r = mf * 16 + lrow;
            const int phys = ((kh * 4 + quad) + r) & 31;
            a[mf] = *(const bf16x8*)&As[r * 256 + phys * 8];
        }
        bf16x8 wf[2];
#pragma unroll
        for (int nf = 0; nf < 2; ++nf)
            wf[nf] = *(const bf16x8*)&Wv[(int64_t)(wv * 32 + nf * 16 + lrow) * 256 + kh * 32 + quad * 8];
#pragma unroll
        for (int mf = 0; mf < 4; ++mf)
#pragma unroll
            for (int nf = 0; nf < 2; ++nf)
                acc[mf][nf] = __builtin_amdgcn_mfma_f32_16x16x32_bf16(a[mf], wf[nf], acc[mf][nf], 0, 0, 0);
    }
    __syncthreads();

    short* Cs = &Sh[wv * 64 * CST];
#pragma unroll
    for (int nf = 0; nf < 2; ++nf)
#pragma unroll
        for (int mf = 0; mf < 4; ++mf)
#pragma unroll
            for (int r = 0; r < 4; ++r)
                Cs[(mf * 16 + quad * 4 + r) * CST + nf * 16 + lrow] = f2b(acc[mf][nf][r] + bia[nf]);
#pragma unroll
    for (int jj = 0; jj < 4; ++jj) {
        const int row = (lane >> 2) + jj * 16;
        const int rr = m0 + row;
        bf16x8 pk = *(const bf16x8*)&Cs[row * CST + (lane & 3) * 8];
        if (rr < Mb)
            *(bf16x8*)&value[(int64_t)rr * 256 + wv * 32 + (lane & 3) * 8] = pk;
    }
}

// ---------------------------------------------------------------------------
// Generalized batched MFMA GEMM. MF = 16-row M-fragments per tile.
// Two-segment bias: col < nsplit -> bias[col], else bias2[col-nsplit].
// ---------------------------------------------------------------------------
template <int NF, int MF, bool DBUF, bool AF32, bool WF32, bool CF32, bool RELU>
__launch_bounds__(256)
__global__ void mfma_gemm(const void* __restrict__ Ap, const void* __restrict__ Wp,
                          const float* __restrict__ bias, void* __restrict__ Cp,
                          int Mb, int N, int K, int tilesM,
                          int ldA, int ldW, int ldC, int nbI,
                          int64_t sAo, int64_t sAi, int64_t sWo, int64_t sWi,
                          int64_t sCo, int64_t sCi, float scale,
                          const float* __restrict__ bias2, int nsplit)
{
    constexpr int BM  = MF * 16;
    constexpr int BN  = 64 * NF;
    constexpr int LDR = 72;
    constexpr int NB  = DBUF ? 2 : 1;
    constexpr int TPR = 256 / BM;
    constexpr int SPT = 64 / TPR;
    constexpr int CHA = SPT / 8;
    __shared__ short As[NB * BM * LDR];
    __shared__ short Ws[NB * BN * LDR];

    const int tid   = threadIdx.x;
    const int batch = blockIdx.y / tilesM;
    const int m0    = (blockIdx.y % tilesM) * BM;
    const int n0    = blockIdx.x * BN;
    const int outer = batch / nbI, inner = batch % nbI;
    const int64_t offA = (int64_t)outer * sAo + (int64_t)inner * sAi;
    const int64_t offW = (int64_t)outer * sWo + (int64_t)inner * sWi;
    const int64_t offC = (int64_t)outer * sCo + (int64_t)inner * sCi;

    const int w = tid >> 6, lane = tid & 63;
    const int quad = lane >> 4, lrow = lane & 15;
    const int colbase = n0 + w * 16 * NF;

    const int smA = tid / TPR;
    const int skA = (tid % TPR) * SPT;
    const int smW = tid >> 2;
    const int skW = (tid & 3) * 16;

    const int T = (K + 63) / 64;

    bf16x8 areg[CHA];
    bf16x8 wreg[2 * NF];

    auto stageA = [&](int t) {
        const int k0 = t * 64;
        const int gm = m0 + smA;
#pragma unroll
        for (int c = 0; c < CHA; ++c) {
            const int k = k0 + skA + c * 8;
            bf16x8 pk = {0, 0, 0, 0, 0, 0, 0, 0};
            if (gm < Mb && k + 8 <= K) {
                if (AF32) {
                    const float* s = (const float*)Ap + offA + (int64_t)gm * ldA + k;
                    float4 u0 = *(const float4*)s;
                    float4 u1 = *(const float4*)(s + 4);
                    pk = (bf16x8){f2b(u0.x), f2b(u0.y), f2b(u0.z), f2b(u0.w),
                                  f2b(u1.x), f2b(u1.y), f2b(u1.z), f2b(u1.w)};
                } else {
                    pk = *(const bf16x8*)((const short*)Ap + offA + (int64_t)gm * ldA + k);
                }
            }
            areg[c] = pk;
        }
    };
    auto stageW = [&](int t) {
        const int k0 = t * 64;
#pragma unroll
        for (int j = 0; j < NF; ++j) {
            const int gn = n0 + j * 64 + smW;
#pragma unroll
            for (int c = 0; c < 2; ++c) {
                const int k = k0 + skW + c * 8;
                bf16x8 pk = {0, 0, 0, 0, 0, 0, 0, 0};
                if (gn < N && k + 8 <= K) {
                    if (WF32) {
                        const float* s = (const float*)Wp + offW + (int64_t)gn * ldW + k;
                        float4 u0 = *(const float4*)s;
                        float4 u1 = *(const float4*)(s + 4);
                        pk = (bf16x8){f2b(u0.x), f2b(u0.y), f2b(u0.z), f2b(u0.w),
                                      f2b(u1.x), f2b(u1.y), f2b(u1.z), f2b(u1.w)};
                    } else {
                        pk = *(const bf16x8*)((const short*)Wp + offW + (int64_t)gn * ldW + k);
                    }
                }
                wreg[j * 2 + c] = pk;
            }
        }
    };
    auto writeLDS = [&](int buf) {
#pragma unroll
        for (int c = 0; c < CHA; ++c)
            *(bf16x8*)&As[(buf * BM + smA) * LDR + skA + c * 8] = areg[c];
#pragma unroll
        for (int j = 0; j < NF; ++j)
#pragma unroll
            for (int c = 0; c < 2; ++c)
                *(bf16x8*)&Ws[(buf * BN + j * 64 + smW) * LDR + skW + c * 8] = wreg[j * 2 + c];
    };

    f32x4 acc[MF][NF];
#pragma unroll
    for (int i = 0; i < MF; ++i)
#pragma unroll
        for (int j = 0; j < NF; ++j) acc[i][j] = (f32x4){0.f, 0.f, 0.f, 0.f};

    auto compute = [&](int buf) {
        bf16x8 a[MF][2], bb[NF][2];
#pragma unroll
        for (int kh = 0; kh < 2; ++kh) {
#pragma unroll
            for (int mf = 0; mf < MF; ++mf)
                a[mf][kh] = *(const bf16x8*)&As[(buf * BM + mf * 16 + lrow) * LDR + kh * 32 + quad * 8];
#pragma unroll
            for (int nf = 0; nf < NF; ++nf)
                bb[nf][kh] = *(const bf16x8*)&Ws[(buf * BN + w * 16 * NF + nf * 16 + lrow) * LDR + kh * 32 + quad * 8];
        }
#pragma unroll
        for (int kh = 0; kh < 2; ++kh)
#pragma unroll
            for (int mf = 0; mf < MF; ++mf)
#pragma unroll
                for (int nf = 0; nf < NF; ++nf)
                    acc[mf][nf] = __builtin_amdgcn_mfma_f32_16x16x32_bf16(a[mf][kh], bb[nf][kh], acc[mf][nf], 0, 0, 0);
    };

    if (DBUF) {
        stageA(0); stageW(0); writeLDS(0);
        __syncthreads();
        for (int t = 0; t < T; ++t) {
            const int cur = t & 1;
            if (t + 1 < T) { stageA(t + 1); stageW(t + 1); }
            compute(cur);
            if (t + 1 < T) {
                writeLDS(cur ^ 1);
                __syncthreads();
            }
        }
    } else {
        for (int t = 0; t < T; ++t) {
            stageA(t); stageW(t);
            if (t > 0) __syncthreads();
            writeLDS(0);
            __syncthreads();
            compute(0);
        }
    }

#pragma unroll
    for (int nf = 0; nf < NF; ++nf) {
        const int col = colbase + nf * 16 + lrow;
        if (col >= N) continue;
        float bia;
        if (col < nsplit) bia = bias ? bias[col] : 0.f;
        else              bia = bias2[col - nsplit];
#pragma unroll
        for (int mf = 0; mf < MF; ++mf) {
            const int row0 = m0 + mf * 16 + quad * 4;
#pragma unroll
            for (int r = 0; r < 4; ++r) {
                const int rr = row0 + r;
                if (rr < Mb) {
                    float v = acc[mf][nf][r] * scale + bia;
                    if (RELU) v = fmaxf(v, 0.f);
                    const int64_t idx = offC + (int64_t)rr * ldC + col;
                    if (CF32) ((float*)Cp)[idx] = v;
                    else      ((short*)Cp)[idx] = f2b(v);
                }
            }
        }
    }
}

template <int NF, int MF, bool DBUF, bool AF32, bool WF32, bool CF32, bool RELU>
static void mfma_launch(const void* A, const void* W, const float* bias, void* Cp,
                        int nb, int nbI, int Mb, int N, int K,
                        int ldA, int ldW, int ldC,
                        int64_t sAo, int64_t sAi, int64_t sWo, int64_t sWi,
                        int64_t sCo, int64_t sCi, float scale, hipStream_t stream,
                        const float* bias2 = nullptr, int nsplit = 1 << 30)
{
    constexpr int BM = MF * 16;
    int tilesM = (Mb + BM - 1) / BM;
    dim3 grid((N + 64 * NF - 1) / (64 * NF), nb * tilesM);
    mfma_gemm<NF, MF, DBUF, AF32, WF32, CF32, RELU><<<grid, 256, 0, stream>>>(
        A, W, bias, Cp, Mb, N, K, tilesM, ldA, ldW, ldC, nbI,
        sAo, sAi, sWo, sWi, sCo, sCi, scale, bias2, nsplit);
}

// ---------------------------------------------------------------------------
// 32x32 tile transpose: dst[b][s][c] (bf16, row=256) = src[b*sbs + (c0+c)*ldS + s]
// ---------------------------------------------------------------------------
__launch_bounds__(256)
__global__ void transpose_kernel(const float* __restrict__ src, short* __restrict__ dst,
                                 int Scount, int ldS, int64_t sbs, int64_t dbs)
{
    const int tid = threadIdx.x;
    const int b = blockIdx.z;
    const int s0 = blockIdx.x * 32, c0 = blockIdx.y * 32;
    __shared__ float t[32][33];
    {
        const int c_l = tid >> 3, sq = (tid & 7) * 4;
        const int64_t base = (int64_t)b * sbs + (int64_t)(c0 + c_l) * ldS;
#pragma unroll
        for (int i = 0; i < 4; ++i) {
            const int s = s0 + sq + i;
            t[c_l][sq + i] = (s < Scount) ? src[base + s] : 0.f;
        }
    }
    __syncthreads();
    {
        const int s_l = tid >> 3, cq = (tid & 7) * 4;
        const int s = s0 + s_l;
        if (s < Scount) {
            s4v pk = {f2b(t[cq + 0][s_l]), f2b(t[cq + 1][s_l]),
                      f2b(t[cq + 2][s_l]), f2b(t[cq + 3][s_l])};
            *(s4v*)&dst[(int64_t)b * dbs + (int64_t)s * 256 + c0 + cq] = pk;
        }
    }
}

// ---------------------------------------------------------------------------
// VT[bh][d][s] (bf16, ld=960, s>=900 zero) from bf16 qkv (B*900, 768)
// ---------------------------------------------------------------------------
__launch_bounds__(256)
__global__ void vt_kernel(const short* __restrict__ qkv, short* __restrict__ VT)
{
    const int tid = threadIdx.x;
    const int bh = blockIdx.y, b = bh >> 3, h = bh & 7;
    const int s0 = blockIdx.x * 32;
    __shared__ short t[32][36];
    {
        const int s_l = tid >> 3, dq = (tid & 7) * 4;
        const int s = s0 + s_l;
        s4v pk = {0, 0, 0, 0};
        if (s < 900)
            pk = *(const s4v*)&qkv[((int64_t)(b * 900 + s)) * 768 + 512 + h * 32 + dq];
        *(s4v*)&t[s_l][dq] = pk;
    }
    __syncthreads();
    {
        const int d = tid >> 3, sq = (tid & 7) * 4;
        s4v pk = {t[sq + 0][d], t[sq + 1][d], t[sq + 2][d], t[sq + 3][d]};
        *(s4v*)&VT[((int64_t)bh * 32 + d) * VLD + s0 + sq] = pk;
    }
}

// ---------------------------------------------------------------------------
// Fused flash-style self-attention. Bounded-score softmax (no running max):
// LN'd activations through 0.02-scale projections -> |score| <~ 1, exp cannot
// overflow; masked s >= 900 -> score -1e30 -> exp = 0.
// ---------------------------------------------------------------------------
__launch_bounds__(256)
__global__ void attn_fused(const short* __restrict__ qkv, const short* __restrict__ VT,
                           short* __restrict__ attno)
{
    __shared__ short Pl[4 * 16 * 72];
    const int tid = threadIdx.x;
    const int wv = tid >> 6, lane = tid & 63;
    const int quad = lane >> 4, lrow = lane & 15;
    const int bh = blockIdx.y, b = bh >> 3, h = bh & 7;
    const int q0 = blockIdx.x * 64 + wv * 16;
    const float iscale = 0.17677669529663687f; // 1/sqrt(32)

    bf16x8 aq = {0, 0, 0, 0, 0, 0, 0, 0};
    {
        const int q = q0 + lrow;
        if (q < 900)
            aq = *(const bf16x8*)&qkv[((int64_t)(b * 900 + q)) * 768 + h * 32 + quad * 8];
    }

    float lsum[4];
    f32x4 o[2] = {{0.f, 0.f, 0.f, 0.f}, {0.f, 0.f, 0.f, 0.f}};
#pragma unroll
    for (int r = 0; r < 4; ++r) lsum[r] = 0.f;

    short* Pw = &Pl[wv * 16 * 72];

    for (int st = 0; st < 15; ++st) {
        const int s0 = st * 64;
        f32x4 sc[4];
#pragma unroll
        for (int nf = 0; nf < 4; ++nf) {
            const int s = s0 + nf * 16 + lrow;
            bf16x8 kb = {0, 0, 0, 0, 0, 0, 0, 0};
            if (s < 900)
                kb = *(const bf16x8*)&qkv[((int64_t)(b * 900 + s)) * 768 + 256 + h * 32 + quad * 8];
            sc[nf] = __builtin_amdgcn_mfma_f32_16x16x32_bf16(aq, kb, (f32x4){0.f, 0.f, 0.f, 0.f}, 0, 0, 0);
        }
#pragma unroll
        for (int nf = 0; nf < 4; ++nf) {
            const int s = s0 + nf * 16 + lrow;
            if (s >= 900) sc[nf] = (f32x4){-1e30f, -1e30f, -1e30f, -1e30f};
            else {
#pragma unroll
                for (int r = 0; r < 4; ++r) sc[nf][r] *= iscale;
            }
        }
        float ps[4][4];
#pragma unroll
        for (int r = 0; r < 4; ++r) {
            float s4 = 0.f;
#pragma unroll
            for (int nf = 0; nf < 4; ++nf) {
                const float p = __expf(sc[nf][r]);
                ps[nf][r] = p;
                s4 += p;
            }
#pragma unroll
            for (int off = 1; off < 16; off <<= 1)
                s4 += __shfl_xor(s4, off, 64);
            lsum[r] += s4;
        }
        // P -> per-wave LDS (C-layout scatter), read back as A-frags
#pragma unroll
        for (int nf = 0; nf < 4; ++nf)
#pragma unroll
            for (int r = 0; r < 4; ++r)
                Pw[(quad * 4 + r) * 72 + nf * 16 + lrow] = f2b(ps[nf][r]);
#pragma unroll
        for (int kh = 0; kh < 2; ++kh) {
            bf16x8 pa = *(const bf16x8*)&Pw[lrow * 72 + kh * 32 + quad * 8];
#pragma unroll
            for (int nf2 = 0; nf2 < 2; ++nf2) {
                const int d = nf2 * 16 + lrow;
                bf16x8 vb = *(const bf16x8*)&VT[((int64_t)bh * 32 + d) * VLD + s0 + kh * 32 + quad * 8];
                o[nf2] = __builtin_amdgcn_mfma_f32_16x16x32_bf16(pa, vb, o[nf2], 0, 0, 0);
            }
        }
    }
#pragma unroll
    for (int r = 0; r < 4; ++r) {
        const int q = q0 + quad * 4 + r;
        if (q < 900) {
            const float inv = 1.f / lsum[r];
#pragma unroll
            for (int nf2 = 0; nf2 < 2; ++nf2)
                attno[((int64_t)(b * 900 + q)) * 256 + h * 32 + nf2 * 16 + lrow] = f2b(o[nf2][r] * inv);
        }
    }
}

// ---------------------------------------------------------------------------
// Residual + LayerNorm over C=256, one block per (b,t). Wave-shfl reduction.
// MODE 0: res = query (B,C,PQ) fp32 transposed-read; out q1 fp32 + q1b bf16
// MODE 1: res = q1 fp32 (BT,C);                      out q2nb bf16 only
// MODE 2: res = q2nb bf16; y = 4 FF2 split-K partials (stride FFS) + eb bias;
//         out d_out fp32 (B,C,PQ)
// ---------------------------------------------------------------------------
template <int MODE>
__launch_bounds__(256)
__global__ void ln_kernel(const float* __restrict__ y, const void* __restrict__ res,
                          const float* __restrict__ g, const float* __restrict__ be,
                          float* __restrict__ out_f, short* __restrict__ out_b,
                          const float* __restrict__ eb)
{
    const int bt = blockIdx.x;
    const int b = bt / PQ_, t = bt % PQ_;
    const int c = threadIdx.x;
    const int wv = c >> 6, lane = c & 63;

    float r;
    if (MODE == 0)      r = ((const float*)res)[((int64_t)b * C_ + c) * PQ_ + t];
    else if (MODE == 1) r = ((const float*)res)[(int64_t)bt * C_ + c];
    else                r = b2f(((const short*)res)[(int64_t)bt * C_ + c]);

    float yv;
    if (MODE == 2) {
        yv = eb[c];
#pragma unroll
        for (int i = 0; i < 4; ++i)
            yv += y[(int64_t)i * FFS + (int64_t)bt * C_ + c];
    } else {
        yv = y[(int64_t)bt * C_ + c];
    }
    const float v = r + yv;

    __shared__ float p1[4], p2[4];
    float a = v, sq = v * v;
#pragma unroll
    for (int off = 32; off > 0; off >>= 1) {
        a  += __shfl_xor(a, off, 64);
        sq += __shfl_xor(sq, off, 64);
    }
    if (lane == 0) { p1[wv] = a; p2[wv] = sq; }
    __syncthreads();
    const float s1 = p1[0] + p1[1] + p1[2] + p1[3];
    const float s2 = p2[0] + p2[1] + p2[2] + p2[3];
    const float mean = s1 * (1.f / C_);
    const float var  = s2 * (1.f / C_) - mean * mean;
    const float o = (v - mean) * rsqrtf(var + 1e-5f) * g[c] + be[c];

    if (MODE == 0) { out_f[(int64_t)bt * C_ + c] = o; out_b[(int64_t)bt * C_ + c] = f2b(o); }
    else if (MODE == 1) out_b[(int64_t)bt * C_ + c] = f2b(o);
    else out_f[((int64_t)b * C_ + c) * PQ_ + t] = o;
}

// ---------------------------------------------------------------------------
// Fused MS-deformable sampling, v3: 512 threads, 2 queries per block, the
// 16 (l,p) samples split across two thread-halves (lph=0 -> levels {0,1},
// lph=1 -> levels {2,3}) to HALVE each thread's serial gather chain (32 vs
// 64 scattered loads); partials combined via a 2 KB LDS reduction.
// Level constants selected by compile-time li + runtime-lph ternaries
// (v_cndmask), never a runtime-indexed local array (no scratch).
// ---------------------------------------------------------------------------
__launch_bounds__(512)
__global__ void deform_kernel(const float* __restrict__ oa,
                              const float* __restrict__ refp, const short* __restrict__ value,
                              short* __restrict__ samp)
{
    const int tid = threadIdx.x;
    const int lph = tid >> 8;            // sample half: levels {0,1} or {2,3}
    const int q   = (tid >> 7) & 1;      // query slot
    const int h   = (tid >> 4) & 7;
    const int dp  = tid & 15;
    const int bt  = blockIdx.x * 2 + q;
    const int b   = bt / PQ_;

    __shared__ float Loff[2][256];
    __shared__ float Law[2][128];
    __shared__ float Lref[2][8];
    __shared__ float Red[2][8][16][2];   // lph=1 partials

    // cooperative loads: 512 threads cover Loff(512), Law(256), Lref(16)
    Loff[tid >> 8][tid & 255] = oa[(int64_t)(blockIdx.x * 2 + (tid >> 8)) * 384 + (tid & 255)];
    if (tid < 256)
        Law[tid >> 7][tid & 127] = oa[(int64_t)(blockIdx.x * 2 + (tid >> 7)) * 384 + 256 + (tid & 127)];
    if (tid < 16)
        Lref[tid >> 3][tid & 7] = refp[(int64_t)(blockIdx.x * 2 + (tid >> 3)) * 8 + (tid & 7)];
    __syncthreads();

    float m = -1e30f;
#pragma unroll
    for (int i = 0; i < 16; ++i) m = fmaxf(m, Law[q][h * 16 + i]);
    float s = 0.f;
#pragma unroll
    for (int i = 0; i < 16; ++i) s += __expf(Law[q][h * 16 + i] - m);
    const float invs = 1.f / s;

    float acc0 = 0.f, acc1 = 0.f;
#pragma unroll
    for (int li = 0; li < 2; ++li) {
        // l = 2*lph + li ; constants via runtime-lph select (no local array)
        const int l   = 2 * lph + li;
        const int Hl  = (lph == 0) ? (li == 0 ? 100 : 50)   : (li == 0 ? 25 : 13);
        const int Wl  = (lph == 0) ? (li == 0 ? 152 : 76)   : (li == 0 ? 38 : 19);
        const int st0 = (lph == 0) ? (li == 0 ? 0 : 15200)  : (li == 0 ? 19000 : 19950);
        const float fx = Lref[q][l * 2 + 0], fy = Lref[q][l * 2 + 1];
#pragma unroll
        for (int p = 0; p < P_; ++p) {
            const float ox = Loff[q][h * 32 + l * 8 + p * 2 + 0];
            const float oy = Loff[q][h * 32 + l * 8 + p * 2 + 1];
            const float x = (fx + ox / (float)Wl) * (float)Wl - 0.5f;
            const float y = (fy + oy / (float)Hl) * (float)Hl - 0.5f;
            const float x0f = floorf(x), y0f = floorf(y);
            const int x0 = (int)x0f, y0 = (int)y0f;
            const float lw = x - x0f, lh = y - y0f;
            const float w00 = (1.f - lw) * (1.f - lh), w10 = lw * (1.f - lh);
            const float w01 = (1.f - lw) * lh,         w11 = lw * lh;
            const float aww = __expf(Law[q][h * 16 + l * 4 + p] - m) * invs;

            float sv0 = 0.f, sv1 = 0.f;
            int ix, iy; float w;
#pragma unroll
            for (int cidx = 0; cidx < 4; ++cidx) {
                if (cidx == 0) { ix = x0;     iy = y0;     w = w00; }
                if (cidx == 1) { ix = x0 + 1; iy = y0;     w = w10; }
                if (cidx == 2) { ix = x0;     iy = y0 + 1; w = w01; }
                if (cidx == 3) { ix = x0 + 1; iy = y0 + 1; w = w11; }
                if (ix >= 0 && ix < Wl && iy >= 0 && iy < Hl) {
                    const int64_t vi = ((int64_t)(b * PK_ + st0 + iy * Wl + ix)) * 256 + h * 32 + dp * 2;
                    const uint32_t pr = *(const uint32_t*)&value[vi];
                    sv0 += w * b2f((short)(pr & 0xffff));
                    sv1 += w * b2f((short)(pr >> 16));
                }
            }
            acc0 += sv0 * aww;
            acc1 += sv1 * aww;
        }
    }

    if (lph == 1) { Red[q][h][dp][0] = acc0; Red[q][h][dp][1] = acc1; }
    __syncthreads();
    if (lph == 0) {
        acc0 += Red[q][h][dp][0];
        acc1 += Red[q][h][dp][1];
        union { uint32_t u; short s2[2]; } o;
        o.s2[0] = f2b(acc0);
        o.s2[1] = f2b(acc1);
        *(uint32_t*)&samp[(int64_t)bt * 256 + h * 32 + dp * 2] = o.u;
    }
}

// ---------------------------------------------------------------------------
extern "C" void kernel_launch(void* const* d_in, const int* in_sizes, int n_in,
                              void* d_out, int out_size, void* d_ws, size_t ws_size,
                              hipStream_t stream)
{
    const float* query = (const float*)d_in[0];
    const float* key   = (const float*)d_in[1];
    const float* refp  = (const float*)d_in[4];
    const float* W_in  = (const float*)d_in[5];
    const float* b_in  = (const float*)d_in[6];
    const float* W_out = (const float*)d_in[7];
    const float* b_out = (const float*)d_in[8];
    const float* W_off = (const float*)d_in[9];
    const float* b_off = (const float*)d_in[10];
    const float* W_aw  = (const float*)d_in[11];
    const float* b_aw  = (const float*)d_in[12];
    const float* W_v   = (const float*)d_in[13];
    const float* b_v   = (const float*)d_in[14];
    const float* W_o   = (const float*)d_in[15];
    const float* b_o   = (const float*)d_in[16];
    const float* W1    = (const float*)d_in[17];
    const float* b1    = (const float*)d_in[18];
    const float* W2    = (const float*)d_in[19];
    const float* b2    = (const float*)d_in[20];
    const float* g1    = (const float*)d_in[21];
    const float* be1   = (const float*)d_in[22];
    const float* g2    = (const float*)d_in[23];
    const float* be2   = (const float*)d_in[24];
    const float* g3    = (const float*)d_in[25];
    const float* be3   = (const float*)d_in[26];

    // Workspace plan:
    //  X [62,259,200]: {qkv bf16 | queryT | VT | attno} -> later ffh
    //  Y: proj ; Z1: q1 ; Wa: q1b -> samp ; Wb: (spare) -> q2nb
    //  VA: value (B*PK,256) bf16 ; WB: bf16 weights
    //  OA: merged offb+awl (BT,384) fp32 ; FFP: 4 FF2 split-K partials
    char* X  = (char*)d_ws;
    char* Yb = X + 62259200;
    char* Z1 = Yb + 7372800;
    char* Wa = Z1 + 7372800;
    char* Wb_ = Wa + 3686400;
    char* VA = Wb_ + 3686400;
    char* WB = VA + 82726912;
    char* OA = WB + 3080192;
    char* FFP = OA + 11059200;

    short* qkvb   = (short*)X;                 // (B*900, 768) bf16
    short* queryT = (short*)(X + 11059200);
    short* VT     = (short*)(X + 14745600);    // 64*32*960*2 = 3,932,160
    short* attno  = (short*)(X + 18677760);
    short* ffh    = (short*)X;
    float* proj   = (float*)Yb;
    float* q1     = (float*)Z1;
    short* q1b    = (short*)Wa;
    short* samp   = (short*)Wa;
    short* q2nb   = (short*)Wb_;
    short* value  = (short*)VA;
    float* oa     = (float*)OA;
    float* ffp    = (float*)FFP;

    short* WBs    = (short*)WB;
    short* Wb_in  = WBs;             // 196608
    short* Wb_out = WBs + 196608;    // 65536
    short* Wb_off = WBs + 262144;    // 65536 (W_aw contiguous after: merged N=384)
    short* Wb_v   = WBs + 360448;    // 65536
    short* Wb_o   = WBs + 425984;    // 65536
    short* Wb1    = WBs + 491520;    // 524288
    short* Wb2    = WBs + 1015808;   // 524288

    // 0. convert all weights fp32 -> bf16 (one launch)
    wcvt_kernel<<<1504, 256, 0, stream>>>(W_in, W_out, W_off, W_aw, W_v, W_o, W1, W2, WBs);
    // 1. queryT = bf16 transpose of query
    transpose_kernel<<<dim3(29, 8, B_), 256, 0, stream>>>(query, queryT, PQ_, PQ_,
                                                          (int64_t)C_ * PQ_, (int64_t)PQ_ * C_);
    // 2. qkv = queryT @ W_in^T + b_in  (bf16 out)
    mfma_launch<1, 4, true, false, false, false, false>(queryT, Wb_in, b_in, qkvb, 1, 1, B_ * PQ_, 768, 256,
                                                        256, 256, 768, 0, 0, 0, 0, 0, 0, 1.f, stream);
    // 3. VT (zero-padded to 960)
    vt_kernel<<<dim3(30, 64), 256, 0, stream>>>(qkvb, VT);
    // 4. fused flash attention -> attno (bf16), bounded-score softmax
    attn_fused<<<dim3(15, 64), 256, 0, stream>>>(qkvb, VT, attno);
    // 5. proj = attno @ W_out^T + b_out  (BM=32)
    mfma_launch<1, 2, true, false, false, true, false>(attno, Wb_out, b_out, proj, 1, 1, B_ * PQ_, 256, 256,
                                                       256, 256, 256, 0, 0, 0, 0, 0, 0, 1.f, stream);
    // 6. q1 = LN(x + proj)  (fp32 + bf16)
    ln_kernel<0><<<B_ * PQ_, 256, 0, stream>>>(proj, query, g1, be1, q1, q1b, nullptr);
    // 7. MERGED offsets + aw-logits GEMM: N=384, BM=32
    mfma_launch<1, 2, true, false, false, true, false>(q1b, Wb_off, b_off, oa, 1, 1, B_ * PQ_, 384, 256,
                                                       256, 256, 384, 0, 0, 0, 0, 0, 0, 1.f, stream,
                                                       b_aw, 256);
    // 8. FUSED key-transpose + value projection v3, then deform v3 (512 thr)
    vgemm3_kernel<<<(B_ * PK_ + 63) / 64, 512, 0, stream>>>(key, Wb_v, b_v, value, B_ * PK_);
    deform_kernel<<<B_ * PQ_ / 2, 512, 0, stream>>>(oa, refp, value, samp);
    // 9. proj2 = samp @ W_o^T + b_o  (reuse proj buffer; BM=32)
    mfma_launch<1, 2, true, false, false, true, false>(samp, Wb_o, b_o, proj, 1, 1, B_ * PQ_, 256, 256,
                                                       256, 256, 256, 0, 0, 0, 0, 0, 0, 1.f, stream);
    // 10. q2nb = LN(q1 + proj2)  (bf16)
    ln_kernel<1><<<B_ * PQ_, 256, 0, stream>>>(proj, q1, g2, be2, nullptr, q2nb, nullptr);
    // 11. ffh = relu(q2nb @ W1^T + b1)  (bf16)
    mfma_launch<1, 4, true, false, false, false, true>(q2nb, Wb1, b1, ffh, 1, 1, B_ * PQ_, FF_, 256,
                                                       256, 256, FF_, 0, 0, 0, 0, 0, 0, 1.f, stream);
    // 12. FF2 split-K=4: 4 partials (no bias), K-chunks of 512 via batch strides
    mfma_launch<1, 4, true, false, false, true, false>(ffh, Wb2, nullptr, ffp, 4, 1, B_ * PQ_, 256, 512,
                                                       FF_, FF_, 256,
                                                       512, 0, 512, 0, FFS, 0, 1.f, stream);
    // 13. d_out = LN(q2nb + sum(ffp) + b2), transposed to (B,C,PQ)
    ln_kernel<2><<<B_ * PQ_, 256, 0, stream>>>(ffp, q2nb, g3, be3, (float*)d_out, nullptr, b2);

    (void)in_sizes; (void)n_in; (void)out_size; (void)ws_size;
}